// Round 2
// baseline (122.413 us; speedup 1.0000x reference)
//
#include <hip/hip_runtime.h>
#include <math.h>

#define S 1024
#define C 4096
#define K 4
#define NSLOT 8

__device__ __forceinline__ float softplusf(float x) {
    return fmaxf(x, 0.0f) + log1pf(expf(-fabsf(x)));
}
__device__ __forceinline__ float logaddexpf_(float a, float b) {
    float mx = fmaxf(a, b), mn = fminf(a, b);
    return mx + log1pf(expf(mn - mx));
}
__device__ __forceinline__ float wave_sum64(float v) {
    for (int o = 32; o > 0; o >>= 1) v += __shfl_down(v, o, 64);
    return v;  // valid in lane 0
}
__device__ __forceinline__ float wave_max64(float v) {
    for (int o = 32; o > 0; o >>= 1) v = fmaxf(v, __shfl_down(v, o, 64));
    return v;  // valid in lane 0
}

// ---------------------------------------------------------------------------
// k_main: 256 blocks x 256 threads. Block b owns rows j = 4b..4b+3 (one per
// wave). Stages the 8 split rows of log_Pi + E in LDS, computes per-slot max
// and w = exp(lp - m) in-block, then each wave makes ONE pass over its
// Recipients_mat row computing 10 dot products:
//   cnt = sum R[j][k];  Edot = sum R[j][k] E[k];  acc[s] = sum R[j][k] w[s][k]
// Emits logE[j] and logTbar[s][j] (= log(max(acc,1e-30)) - log(cnt) + m[s]).
// ---------------------------------------------------------------------------
__global__ __launch_bounds__(256) void k_main(
    const float* __restrict__ E, const float* __restrict__ logPi,
    const float* __restrict__ Recip,
    const int* __restrict__ sC1, const int* __restrict__ sC2,
    const int* __restrict__ sp1, const int* __restrict__ sp2,
    const int* __restrict__ rootp,
    const float* __restrict__ ld, const float* __restrict__ lt,
    const float* __restrict__ ll,
    float* __restrict__ logE, float* __restrict__ logTbar) {
    __shared__ __align__(16) float w[NSLOT][S];  // 32 KB: rows, then exp in place
    __shared__ __align__(16) float els[S];       // 4 KB
    __shared__ float msh[NSLOT];
    int t = threadIdx.x;
    int root = rootp[0];

    for (int slot = 0; slot < NSLOT; ++slot) {
        int row = (slot < K) ? sp1[root * K + slot] : sp2[root * K + (slot - K)];
        const float* src = logPi + (size_t)row * S;
        for (int k = t; k < S; k += 256) w[slot][k] = src[k];
    }
    for (int k = t; k < S; k += 256) els[k] = E[k];
    __syncthreads();

    int wave = t >> 6, lane = t & 63;
    // per-slot max: wave handles slots 2*wave, 2*wave+1
    for (int s2 = 0; s2 < 2; ++s2) {
        int slot = wave * 2 + s2;
        float m = -INFINITY;
        for (int k = lane; k < S; k += 64) m = fmaxf(m, w[slot][k]);
        m = wave_max64(m);
        if (lane == 0) msh[slot] = m;
    }
    __syncthreads();
    for (int slot = 0; slot < NSLOT; ++slot) {
        float m = msh[slot];
        for (int k = t; k < S; k += 256) w[slot][k] = expf(w[slot][k] - m);
    }
    __syncthreads();

    // one pass over Recipients_mat row j (float4)
    int j = blockIdx.x * 4 + wave;
    const float4* rrow = (const float4*)(Recip + (size_t)j * S);
    const float4* ev4 = (const float4*)els;
    float4 aw[NSLOT];
    float4 ac = make_float4(0.f, 0.f, 0.f, 0.f);
    float4 ae = make_float4(0.f, 0.f, 0.f, 0.f);
#pragma unroll
    for (int s = 0; s < NSLOT; ++s) aw[s] = make_float4(0.f, 0.f, 0.f, 0.f);

#pragma unroll
    for (int i0 = 0; i0 < S / 4; i0 += 64) {
        int i = i0 + lane;
        float4 r = rrow[i];
        float4 e = ev4[i];
        ac.x += r.x; ac.y += r.y; ac.z += r.z; ac.w += r.w;
        ae.x += r.x * e.x; ae.y += r.y * e.y; ae.z += r.z * e.z; ae.w += r.w * e.w;
#pragma unroll
        for (int s = 0; s < NSLOT; ++s) {
            float4 wv = ((const float4*)w[s])[i];
            aw[s].x += r.x * wv.x; aw[s].y += r.y * wv.y;
            aw[s].z += r.z * wv.z; aw[s].w += r.w * wv.w;
        }
    }
    float c = wave_sum64(ac.x + ac.y + ac.z + ac.w);
    float ed = wave_sum64(ae.x + ae.y + ae.z + ae.w);
    float as[NSLOT];
#pragma unroll
    for (int s = 0; s < NSLOT; ++s)
        as[s] = wave_sum64(aw[s].x + aw[s].y + aw[s].z + aw[s].w);

    if (lane == 0) {
        float cnt = fmaxf(c, 1.0f);
        float logCnt = logf(cnt);
#pragma unroll
        for (int s = 0; s < NSLOT; ++s)
            logTbar[s * S + j] = logf(fmaxf(as[s], 1e-30f)) - logCnt + msh[s];
        float delta = softplusf(ld[0]);
        float tau = softplusf(lt[0]);
        float lam = softplusf(ll[0]);
        float rs = 1.0f + delta + tau + lam;
        float pS = 1.0f / rs, pD = delta / rs, pT = tau / rs, pL = lam / rs;
        float Ej = els[j];
        float en = pL + pD * Ej * Ej + pT * Ej * (ed / cnt)
                 + pS * els[sC1[j]] * els[sC2[j]];
        logE[j] = logf(en);
    }
}

// ---------------------------------------------------------------------------
// k_final: root row combine + block-wide logsumexp. 1 block x 1024 threads.
// ---------------------------------------------------------------------------
__global__ __launch_bounds__(1024) void k_final(
    const float* __restrict__ logPi, const int* __restrict__ sC1,
    const int* __restrict__ sC2, const int* __restrict__ sp1,
    const int* __restrict__ sp2, const float* __restrict__ logq,
    const void* __restrict__ isLeaf, const int* __restrict__ rootp,
    const float* __restrict__ ld, const float* __restrict__ lt,
    const float* __restrict__ ll,
    const float* __restrict__ logE, const float* __restrict__ logTbar,
    float* __restrict__ out) {
    __shared__ float sA[NSLOT][S];
    __shared__ float sLogE[S];
    __shared__ float sRoot[S];
    __shared__ float red[1024];
    int t = threadIdx.x;
    int root = rootp[0];

    for (int slot = 0; slot < NSLOT; ++slot) {
        int row = (slot < K) ? sp1[root * K + slot] : sp2[root * K + (slot - K)];
        sA[slot][t] = logPi[(size_t)row * S + t];
    }
    sLogE[t] = logE[t];
    sRoot[t] = logPi[(size_t)root * S + t];
    __syncthreads();

    float delta = softplusf(ld[0]);
    float tau = softplusf(lt[0]);
    float lam = softplusf(ll[0]);
    float rs = 1.0f + delta + tau + lam;
    float lpS = logf(1.0f / rs), lpD = logf(delta / rs), lpT = logf(tau / rs);

    int j = t;
    int f = sC1[j], g = sC2[j];

    float vs[K], vd[K], vt[K];
    float ms = -INFINITY, md = -INFINITY, mt = -INFINITY;
#pragma unroll
    for (int k = 0; k < K; ++k) {
        float lq = logq[root * K + k];
        float Aj = sA[k][j], Bj = sA[4 + k][j];
        float Af = sA[k][f], Ag = sA[k][g];
        float Bf = sA[4 + k][f], Bg = sA[4 + k][g];
        vs[k] = lq + logaddexpf_(Af + Bg, Ag + Bf);
        vd[k] = lq + Aj + Bj;
        float TbAj = logTbar[k * S + j];
        float TbBj = logTbar[(4 + k) * S + j];
        vt[k] = lq + logaddexpf_(Aj + TbBj, Bj + TbAj);
        ms = fmaxf(ms, vs[k]); md = fmaxf(md, vd[k]); mt = fmaxf(mt, vt[k]);
    }
    float ss = 0.f, sd_ = 0.f, st = 0.f;
#pragma unroll
    for (int k = 0; k < K; ++k) {
        ss += expf(vs[k] - ms);
        sd_ += expf(vd[k] - md);
        st += expf(vt[k] - mt);
    }
    float vspec = lpS + ms + logf(ss);
    float vdup = lpD + md + logf(sd_);
    float vtrans = lpT + mt + logf(st);
    float vsl = lpS + logaddexpf_(sRoot[f] + sLogE[g], sRoot[g] + sLogE[f]);

    float cm = fmaxf(fmaxf(vspec, vdup), fmaxf(vtrans, vsl));
    float comb = cm + logf(expf(vspec - cm) + expf(vdup - cm) +
                           expf(vtrans - cm) + expf(vsl - cm));

    unsigned int u = ((const unsigned int*)isLeaf)[root];
    bool leaf = ((u & 0xFFu) != 0u) || (u == 0x3F800000u);
    float x = leaf ? sRoot[j] : comb;

    red[t] = x;
    __syncthreads();
    for (int o = 512; o > 0; o >>= 1) {
        if (t < o) red[t] = fmaxf(red[t], red[t + o]);
        __syncthreads();
    }
    float m = red[0];
    __syncthreads();
    red[t] = expf(x - m);
    __syncthreads();
    for (int o = 512; o > 0; o >>= 1) {
        if (t < o) red[t] += red[t + o];
        __syncthreads();
    }
    if (t == 0) out[0] = m + logf(red[0]);
}

extern "C" void kernel_launch(void* const* d_in, const int* in_sizes, int n_in,
                              void* d_out, int out_size, void* d_ws, size_t ws_size,
                              hipStream_t stream) {
    const float* log_delta = (const float*)d_in[0];
    const float* log_tau = (const float*)d_in[1];
    const float* log_lambda = (const float*)d_in[2];
    const float* E = (const float*)d_in[3];
    const float* log_Pi = (const float*)d_in[4];
    const int* s_C1 = (const int*)d_in[5];
    const int* s_C2 = (const int*)d_in[6];
    const float* Recip = (const float*)d_in[7];
    const int* splits_c1 = (const int*)d_in[8];
    const int* splits_c2 = (const int*)d_in[9];
    const float* log_q = (const float*)d_in[10];
    const void* is_leaf = (const void*)d_in[11];
    const int* root_id = (const int*)d_in[12];
    float* out = (float*)d_out;

    float* ws = (float*)d_ws;
    float* logE = ws;                 // S
    float* logTbar = ws + S;          // 8*S

    k_main<<<dim3(S / 4), dim3(256), 0, stream>>>(
        E, log_Pi, Recip, s_C1, s_C2, splits_c1, splits_c2, root_id,
        log_delta, log_tau, log_lambda, logE, logTbar);
    k_final<<<dim3(1), dim3(1024), 0, stream>>>(
        log_Pi, s_C1, s_C2, splits_c1, splits_c2, log_q, is_leaf, root_id,
        log_delta, log_tau, log_lambda, logE, logTbar, out);
}